// Round 1
// baseline (146.807 us; speedup 1.0000x reference)
//
#include <hip/hip_runtime.h>

// Problem constants (from reference setup_inputs)
#define BB 8
#define CC 128
#define HH 128
#define WW 128
#define PLANE (HH * WW)      // 16384
#define KK 9                 // 3x3

// ---------------------------------------------------------------------------
// Kernel 1: global average pool per (b,c) plane.
// 1024 blocks (one per plane) x 256 threads; each thread sums 16 float4s.
// ---------------------------------------------------------------------------
__global__ __launch_bounds__(256) void pool_kernel(const float* __restrict__ x,
                                                   float* __restrict__ pooled) {
    int bc = blockIdx.x;
    const float4* p4 = (const float4*)(x + (size_t)bc * PLANE);
    int t = threadIdx.x;
    float s = 0.f;
#pragma unroll
    for (int i = 0; i < 16; ++i) {
        float4 v = p4[t + i * 256];
        s += v.x + v.y + v.z + v.w;
    }
    // wave (64-lane) shuffle reduce
#pragma unroll
    for (int off = 32; off > 0; off >>= 1) s += __shfl_down(s, off, 64);
    __shared__ float wsum[4];
    int wave = t >> 6, lane = t & 63;
    if (lane == 0) wsum[wave] = s;
    __syncthreads();
    if (t == 0) {
        float tot = wsum[0] + wsum[1] + wsum[2] + wsum[3];
        pooled[bc] = tot * (1.0f / PLANE);
    }
}

// ---------------------------------------------------------------------------
// Kernel 2: kernel generator. h = relu(pooled @ w1^T + b1); kern = h @ w2^T + b2.
// Grid 8*9 blocks x 128 threads. Each block redundantly computes h[b,:] in LDS
// (128x128 MACs, trivial), then its 128 kern outputs.
// ---------------------------------------------------------------------------
__global__ __launch_bounds__(128) void kerngen_kernel(const float* __restrict__ pooled,
                                                      const float* __restrict__ w1,
                                                      const float* __restrict__ b1,
                                                      const float* __restrict__ w2,
                                                      const float* __restrict__ b2,
                                                      float* __restrict__ kern) {
    int b = blockIdx.x / 9;
    int g = blockIdx.x % 9;
    int j = threadIdx.x;
    __shared__ float ps[CC];
    __shared__ float hs[CC];
    ps[j] = pooled[b * CC + j];
    __syncthreads();
    float acc = b1[j];
    const float* w1r = w1 + j * CC;
#pragma unroll 8
    for (int i = 0; i < CC; ++i) acc += ps[i] * w1r[i];
    hs[j] = fmaxf(acc, 0.f);
    __syncthreads();
    int o = g * CC + j;              // [0, 1152)
    float acc2 = b2[o];
    const float* w2r = w2 + o * CC;
#pragma unroll 8
    for (int i = 0; i < CC; ++i) acc2 += hs[i] * w2r[i];
    kern[b * (CC * KK) + o] = acc2;  // layout: [B][C*9] == [bc*9 + p]
}

// ---------------------------------------------------------------------------
// Kernel 3: dynamic depthwise 3x3 conv (cross-correlation, zero pad).
// Grid B*C*4 blocks (4 row-slices of 32 rows each) x 256 threads.
// Each thread computes 4 float4 output chunks.
// ---------------------------------------------------------------------------
__global__ __launch_bounds__(256) void conv_kernel(const float* __restrict__ x,
                                                   const float* __restrict__ kern,
                                                   float* __restrict__ out) {
    int bid = blockIdx.x;
    int bc = bid >> 2, slice = bid & 3;
    const float* plane = x + (size_t)bc * PLANE;
    float* oplane = out + (size_t)bc * PLANE;
    const float* wp = kern + (size_t)bc * KK;
    float w[9];
#pragma unroll
    for (int p = 0; p < 9; ++p) w[p] = wp[p];
    int t = threadIdx.x;
#pragma unroll
    for (int i = 0; i < 4; ++i) {
        int q = slice * 1024 + i * 256 + t;   // float4 chunk index in plane
        int y = q >> 5;                        // 32 float4 per row
        int xq = q & 31;
        int x0 = xq << 2;
        float4 acc = {0.f, 0.f, 0.f, 0.f};
#pragma unroll
        for (int ky = 0; ky < 3; ++ky) {
            int yr = y + ky - 1;
            if (yr < 0 || yr >= HH) continue;  // zero padding rows
            const float* row = plane + yr * WW;
            float4 c = *(const float4*)(row + x0);
            float l = (x0 > 0) ? row[x0 - 1] : 0.f;
            float r = (xq < 31) ? row[x0 + 4] : 0.f;
            float w0 = w[ky * 3 + 0], w1_ = w[ky * 3 + 1], w2_ = w[ky * 3 + 2];
            acc.x += w0 * l   + w1_ * c.x + w2_ * c.y;
            acc.y += w0 * c.x + w1_ * c.y + w2_ * c.z;
            acc.z += w0 * c.y + w1_ * c.z + w2_ * c.w;
            acc.w += w0 * c.z + w1_ * c.w + w2_ * r;
        }
        *(float4*)(oplane + y * WW + x0) = acc;
    }
}

// ---------------------------------------------------------------------------
extern "C" void kernel_launch(void* const* d_in, const int* in_sizes, int n_in,
                              void* d_out, int out_size, void* d_ws, size_t ws_size,
                              hipStream_t stream) {
    const float* x  = (const float*)d_in[0];
    const float* w1 = (const float*)d_in[1];
    const float* b1 = (const float*)d_in[2];
    const float* w2 = (const float*)d_in[3];
    const float* b2 = (const float*)d_in[4];
    float* out = (float*)d_out;

    float* ws = (float*)d_ws;
    float* pooled = ws;          // B*C = 1024 floats
    float* kern   = ws + 1024;   // B*C*9 = 9216 floats

    pool_kernel<<<BB * CC, 256, 0, stream>>>(x, pooled);
    kerngen_kernel<<<BB * 9, 128, 0, stream>>>(pooled, w1, b1, w2, b2, kern);
    conv_kernel<<<BB * CC * 4, 256, 0, stream>>>(x, kern, out);
}

// Round 2
// 144.371 us; speedup vs baseline: 1.0169x; 1.0169x over previous
//
#include <hip/hip_runtime.h>

// Problem constants (from reference setup_inputs)
#define BB 8
#define CC 128
#define HH 128
#define WW 128
#define PLANE (HH * WW)      // 16384
#define KK 9                 // 3x3

// ---------------------------------------------------------------------------
// Kernel 1: global average pool per (b,c) plane.
// 1024 blocks (one per plane) x 256 threads; each thread sums 16 float4s.
// ---------------------------------------------------------------------------
__global__ __launch_bounds__(256) void pool_kernel(const float* __restrict__ x,
                                                   float* __restrict__ pooled) {
    int bc = blockIdx.x;
    const float4* p4 = (const float4*)(x + (size_t)bc * PLANE);
    int t = threadIdx.x;
    float s = 0.f;
#pragma unroll
    for (int i = 0; i < 16; ++i) {
        float4 v = p4[t + i * 256];
        s += v.x + v.y + v.z + v.w;
    }
#pragma unroll
    for (int off = 32; off > 0; off >>= 1) s += __shfl_down(s, off, 64);
    __shared__ float wsum[4];
    int wave = t >> 6, lane = t & 63;
    if (lane == 0) wsum[wave] = s;
    __syncthreads();
    if (t == 0) {
        pooled[bc] = (wsum[0] + wsum[1] + wsum[2] + wsum[3]) * (1.0f / PLANE);
    }
}

// ---------------------------------------------------------------------------
// Kernel 2 (fused): per-(b,c) block computes h[b,:] (redundantly), its 9-tap
// dynamic kernel, then the depthwise 3x3 conv over its plane.
// Grid: B*C = 512 blocks x 512 threads.
// ---------------------------------------------------------------------------
__global__ __launch_bounds__(512, 4) void fused_conv_kernel(
        const float* __restrict__ x,
        const float* __restrict__ pooled,
        const float* __restrict__ w1,
        const float* __restrict__ b1,
        const float* __restrict__ w2,
        const float* __restrict__ b2,
        float* __restrict__ out) {
    int bc = blockIdx.x;
    int b = bc >> 7;           // / CC
    int c = bc & 127;
    int t = threadIdx.x;

    __shared__ float hs[CC];
    __shared__ float ks[KK];

    // ---- Phase A: h[j] = relu(sum_i pooled[b][i] * w1[j][i] + b1[j]) ----
    {
        int j = t >> 2;        // 0..127  output channel
        int k = t & 3;         // 0..3    quarter of the dot
        const float* pr = pooled + b * CC + k * 32;
        const float* wr = w1 + j * CC + k * 32;
        float a = 0.f;
#pragma unroll
        for (int i = 0; i < 32; ++i) a += pr[i] * wr[i];
        a += __shfl_down(a, 1, 64);
        a += __shfl_down(a, 2, 64);
        if (k == 0) hs[j] = fmaxf(a + b1[j], 0.f);
    }
    __syncthreads();

    // ---- Phase B: ks[p] = hs . w2[c*9+p] + b2[c*9+p], one wave per p ----
    {
        int w = t >> 6, lane = t & 63;
        for (int p = w; p < KK; p += 8) {
            int o = c * KK + p;
            const float* wr = w2 + o * CC;
            float a = hs[lane] * wr[lane] + hs[lane + 64] * wr[lane + 64];
#pragma unroll
            for (int off = 32; off > 0; off >>= 1) a += __shfl_down(a, off, 64);
            if (lane == 0) ks[p] = a + b2[o];
        }
    }
    __syncthreads();

    float w[9];
#pragma unroll
    for (int p = 0; p < 9; ++p) w[p] = ks[p];

    // ---- Phase C: depthwise 3x3, sliding window over an 8-row column strip --
    const float* plane = x + (size_t)bc * PLANE;
    float* oplane = out + (size_t)bc * PLANE;
    int xq = t & 31;           // float4 column chunk
    int x0 = xq << 2;
    int yb = (t >> 5) * 8;     // 16 groups * 8 rows = 128 rows

    float4 A = {0.f, 0.f, 0.f, 0.f};   // partial for out row yr-1
    float4 Bv = {0.f, 0.f, 0.f, 0.f};  // partial for out row yr

#pragma unroll
    for (int s = 0; s < 10; ++s) {
        int yr = yb - 1 + s;
        float4 cv = {0.f, 0.f, 0.f, 0.f};
        float l = 0.f, r = 0.f;
        if (yr >= 0 && yr < HH) {
            const float* row = plane + yr * WW;
            cv = *(const float4*)(row + x0);
            l = (xq > 0) ? row[x0 - 1] : 0.f;
            r = (xq < 31) ? row[x0 + 4] : 0.f;
        }
        // shifted products for the three weight rows
        // p_bot (ky=2) completes out[yr-1]; p_mid (ky=1) -> out[yr]; p_top (ky=0) -> out[yr+1]
        float4 pbot, pmid, ptop;
        pbot.x = w[6]*l    + w[7]*cv.x + w[8]*cv.y;
        pbot.y = w[6]*cv.x + w[7]*cv.y + w[8]*cv.z;
        pbot.z = w[6]*cv.y + w[7]*cv.z + w[8]*cv.w;
        pbot.w = w[6]*cv.z + w[7]*cv.w + w[8]*r;
        pmid.x = w[3]*l    + w[4]*cv.x + w[5]*cv.y;
        pmid.y = w[3]*cv.x + w[4]*cv.y + w[5]*cv.z;
        pmid.z = w[3]*cv.y + w[4]*cv.z + w[5]*cv.w;
        pmid.w = w[3]*cv.z + w[4]*cv.w + w[5]*r;
        ptop.x = w[0]*l    + w[1]*cv.x + w[2]*cv.y;
        ptop.y = w[0]*cv.x + w[1]*cv.y + w[2]*cv.z;
        ptop.z = w[0]*cv.y + w[1]*cv.z + w[2]*cv.w;
        ptop.w = w[0]*cv.z + w[1]*cv.w + w[2]*r;

        A.x += pbot.x; A.y += pbot.y; A.z += pbot.z; A.w += pbot.w;
        int yo = yr - 1;
        if (yo >= yb && yo < yb + 8) {
            *(float4*)(oplane + yo * WW + x0) = A;
        }
        Bv.x += pmid.x; Bv.y += pmid.y; Bv.z += pmid.z; Bv.w += pmid.w;
        A = Bv;
        Bv = ptop;
    }
}

// ---------------------------------------------------------------------------
extern "C" void kernel_launch(void* const* d_in, const int* in_sizes, int n_in,
                              void* d_out, int out_size, void* d_ws, size_t ws_size,
                              hipStream_t stream) {
    const float* x  = (const float*)d_in[0];
    const float* w1 = (const float*)d_in[1];
    const float* b1 = (const float*)d_in[2];
    const float* w2 = (const float*)d_in[3];
    const float* b2 = (const float*)d_in[4];
    float* out = (float*)d_out;

    float* pooled = (float*)d_ws;   // B*C = 1024 floats

    pool_kernel<<<BB * CC, 256, 0, stream>>>(x, pooled);
    fused_conv_kernel<<<BB * CC, 512, 0, stream>>>(x, pooled, w1, b1, w2, b2, out);
}

// Round 3
// 138.016 us; speedup vs baseline: 1.0637x; 1.0460x over previous
//
#include <hip/hip_runtime.h>

// Problem constants (from reference setup_inputs)
#define BB 8
#define CC 128
#define HH 128
#define WW 128
#define PLANE (HH * WW)      // 16384
#define KK 9                 // 3x3

// ---------------------------------------------------------------------------
// Kernel 1: global average pool per (b,c) plane.
// 1024 blocks (one per plane) x 512 threads (8 waves -> full occupancy);
// each thread sums 8 float4s.
// ---------------------------------------------------------------------------
__global__ __launch_bounds__(512) void pool_kernel(const float* __restrict__ x,
                                                   float* __restrict__ pooled) {
    int bc = blockIdx.x;
    const float4* p4 = (const float4*)(x + (size_t)bc * PLANE);
    int t = threadIdx.x;
    float s = 0.f;
#pragma unroll
    for (int i = 0; i < 8; ++i) {
        float4 v = p4[t + i * 512];
        s += v.x + v.y + v.z + v.w;
    }
#pragma unroll
    for (int off = 32; off > 0; off >>= 1) s += __shfl_down(s, off, 64);
    __shared__ float wsum[8];
    int wave = t >> 6, lane = t & 63;
    if (lane == 0) wsum[wave] = s;
    __syncthreads();
    if (t == 0) {
        float tot = 0.f;
#pragma unroll
        for (int i = 0; i < 8; ++i) tot += wsum[i];
        pooled[bc] = tot * (1.0f / PLANE);
    }
}

// ---------------------------------------------------------------------------
// Kernel 2: kernel generator. h = relu(pooled @ w1^T + b1); kern = h @ w2^T + b2.
// Grid 8*9 blocks x 128 threads; each block redundantly computes h[b,:] in LDS.
// Tiny (~3 us), runs while nothing else is pending.
// ---------------------------------------------------------------------------
__global__ __launch_bounds__(128) void kerngen_kernel(const float* __restrict__ pooled,
                                                      const float* __restrict__ w1,
                                                      const float* __restrict__ b1,
                                                      const float* __restrict__ w2,
                                                      const float* __restrict__ b2,
                                                      float* __restrict__ kern) {
    int b = blockIdx.x / 9;
    int g = blockIdx.x % 9;
    int j = threadIdx.x;
    __shared__ float ps[CC];
    __shared__ float hs[CC];
    ps[j] = pooled[b * CC + j];
    __syncthreads();
    float acc = b1[j];
    const float* w1r = w1 + j * CC;
#pragma unroll 8
    for (int i = 0; i < CC; ++i) acc += ps[i] * w1r[i];
    hs[j] = fmaxf(acc, 0.f);
    __syncthreads();
    int o = g * CC + j;              // [0, 1152)
    float acc2 = b2[o];
    const float* w2r = w2 + o * CC;
#pragma unroll 8
    for (int i = 0; i < CC; ++i) acc2 += hs[i] * w2r[i];
    kern[b * (CC * KK) + o] = acc2;  // layout [b][c*9+p]
}

// ---------------------------------------------------------------------------
// Kernel 3: dynamic depthwise 3x3 conv (cross-correlation, zero pad).
// Grid B*C*4 = 2048 blocks x 256 threads (8 blocks/CU -> full occupancy).
// Each thread: sliding window over a 4-row x 4-col strip (6 row loads).
// ---------------------------------------------------------------------------
__global__ __launch_bounds__(256) void conv_kernel(const float* __restrict__ x,
                                                   const float* __restrict__ kern,
                                                   float* __restrict__ out) {
    int bid = blockIdx.x;
    int bc = bid >> 2, slice = bid & 3;
    const float* plane = x + (size_t)bc * PLANE;
    float* oplane = out + (size_t)bc * PLANE;
    const float* wp = kern + (size_t)bc * KK;
    float w[9];
#pragma unroll
    for (int p = 0; p < 9; ++p) w[p] = wp[p];

    int t = threadIdx.x;
    int xq = t & 31;               // float4 column chunk
    int x0 = xq << 2;
    int yb = slice * 32 + (t >> 5) * 4;   // 8 row-groups of 4 rows

    float4 A  = {0.f, 0.f, 0.f, 0.f};  // partial for out row yr-1
    float4 Bv = {0.f, 0.f, 0.f, 0.f};  // partial for out row yr

#pragma unroll
    for (int s = 0; s < 6; ++s) {
        int yr = yb - 1 + s;
        float4 cv = {0.f, 0.f, 0.f, 0.f};
        float l = 0.f, r = 0.f;
        if (yr >= 0 && yr < HH) {
            const float* row = plane + yr * WW;
            cv = *(const float4*)(row + x0);
            l = (xq > 0) ? row[x0 - 1] : 0.f;
            r = (xq < 31) ? row[x0 + 4] : 0.f;
        }
        // shifted products: pbot completes out[yr-1]; pmid -> out[yr]; ptop -> out[yr+1]
        float4 pbot, pmid, ptop;
        pbot.x = w[6]*l    + w[7]*cv.x + w[8]*cv.y;
        pbot.y = w[6]*cv.x + w[7]*cv.y + w[8]*cv.z;
        pbot.z = w[6]*cv.y + w[7]*cv.z + w[8]*cv.w;
        pbot.w = w[6]*cv.z + w[7]*cv.w + w[8]*r;
        pmid.x = w[3]*l    + w[4]*cv.x + w[5]*cv.y;
        pmid.y = w[3]*cv.x + w[4]*cv.y + w[5]*cv.z;
        pmid.z = w[3]*cv.y + w[4]*cv.z + w[5]*cv.w;
        pmid.w = w[3]*cv.z + w[4]*cv.w + w[5]*r;
        ptop.x = w[0]*l    + w[1]*cv.x + w[2]*cv.y;
        ptop.y = w[0]*cv.x + w[1]*cv.y + w[2]*cv.z;
        ptop.z = w[0]*cv.y + w[1]*cv.z + w[2]*cv.w;
        ptop.w = w[0]*cv.z + w[1]*cv.w + w[2]*r;

        A.x += pbot.x; A.y += pbot.y; A.z += pbot.z; A.w += pbot.w;
        int yo = yr - 1;                    // s>=2 <=> yo in [yb, yb+4): compile-time per unrolled s
        if (yo >= yb && yo < yb + 4) {
            *(float4*)(oplane + yo * WW + x0) = A;
        }
        Bv.x += pmid.x; Bv.y += pmid.y; Bv.z += pmid.z; Bv.w += pmid.w;
        A = Bv;
        Bv = ptop;
    }
}

// ---------------------------------------------------------------------------
extern "C" void kernel_launch(void* const* d_in, const int* in_sizes, int n_in,
                              void* d_out, int out_size, void* d_ws, size_t ws_size,
                              hipStream_t stream) {
    const float* x  = (const float*)d_in[0];
    const float* w1 = (const float*)d_in[1];
    const float* b1 = (const float*)d_in[2];
    const float* w2 = (const float*)d_in[3];
    const float* b2 = (const float*)d_in[4];
    float* out = (float*)d_out;

    float* ws = (float*)d_ws;
    float* pooled = ws;          // B*C = 1024 floats
    float* kern   = ws + 1024;   // B*C*9 = 9216 floats

    pool_kernel<<<BB * CC, 512, 0, stream>>>(x, pooled);
    kerngen_kernel<<<BB * 9, 128, 0, stream>>>(pooled, w1, b1, w2, b2, kern);
    conv_kernel<<<BB * CC * 4, 256, 0, stream>>>(x, kern, out);
}